// Round 1
// baseline (161.402 us; speedup 1.0000x reference)
//
#include <hip/hip_runtime.h>
#include <hip/hip_fp16.h>
#include <math.h>

// N = 160000 = 256 * 625; four-step FFT decomposition.
// R16 = R15 with f2+i1 fused (fi_kernel): forward DIF-256 of each k2-row into
// LDS, then 8x {LDS-local band mask -> inverse DIF-256 -> chained epilogue ->
// fp16 H}. Eliminates the X global round-trip (20.5 MB) and one launch.
// f1: pack w+i*o (float4), per-wave in-place DIF-625 (chained twiddles) -> G[k2][n1];
//     zeroes E. Epilogue twiddle chained over k2 steps of 64.
// fi: per-wave forward DIF-256 (pad8) of G-row; per band: masked LDS copy,
//     inverse DIF-256, block-transposed chained epilogue -> fp16 H[n1][k2] (1/L).
// i2: one wave per column, 2 fp16 columns prefetched, cached stage twiddles,
//     per-wave LDS partials, single barrier.
constexpr int L      = 160000;
constexpr int BATCH  = 8;
constexpr int NB     = 8;
constexpr int NHOPS  = 156;
constexpr int NCHUNK = 155;
constexpr int RS     = 289;   // swizzled row stride
constexpr float TWO_PI = 6.28318530717958647692f;
constexpr float INVL = 1.0f / (float)L;

__device__ __forceinline__ float2 cmulf(float2 a, float2 b) {
  return make_float2(a.x * b.x - a.y * b.y, a.x * b.y + a.y * b.x);
}

__device__ __forceinline__ float2 cisf(float a) {
  float s, c;
  __sincosf(a, &s, &c);
  return make_float2(c, s);
}

__device__ __forceinline__ int pad8(int i) { return i + (i >> 3); }

template <int SIGN>
__device__ __forceinline__ void bf4s(float2* v) {
  float2 t0 = make_float2(v[0].x + v[2].x, v[0].y + v[2].y);
  float2 t1 = make_float2(v[0].x - v[2].x, v[0].y - v[2].y);
  float2 t2 = make_float2(v[1].x + v[3].x, v[1].y + v[3].y);
  float2 t3 = make_float2(v[1].x - v[3].x, v[1].y - v[3].y);
  v[0] = make_float2(t0.x + t2.x, t0.y + t2.y);
  v[2] = make_float2(t0.x - t2.x, t0.y - t2.y);
  if constexpr (SIGN < 0) {
    v[1] = make_float2(t1.x + t3.y, t1.y - t3.x);
    v[3] = make_float2(t1.x - t3.y, t1.y + t3.x);
  } else {
    v[1] = make_float2(t1.x - t3.y, t1.y + t3.x);
    v[3] = make_float2(t1.x + t3.y, t1.y - t3.x);
  }
}

template <int SIGN>
__device__ __forceinline__ void bf5s(float2* v) {
  const float c1 = 0.30901699437494745f, s1 = 0.9510565162951535f;
  const float c2 = -0.8090169943749475f, s2 = 0.5877852522924731f;
  float2 t1 = make_float2(v[1].x + v[4].x, v[1].y + v[4].y);
  float2 t3 = make_float2(v[1].x - v[4].x, v[1].y - v[4].y);
  float2 t2 = make_float2(v[2].x + v[3].x, v[2].y + v[3].y);
  float2 t4 = make_float2(v[2].x - v[3].x, v[2].y - v[3].y);
  float2 a = make_float2(v[0].x + c1 * t1.x + c2 * t2.x, v[0].y + c1 * t1.y + c2 * t2.y);
  float2 b = make_float2(s1 * t3.x + s2 * t4.x, s1 * t3.y + s2 * t4.y);
  float2 c = make_float2(v[0].x + c2 * t1.x + c1 * t2.x, v[0].y + c2 * t1.y + c1 * t2.y);
  float2 d = make_float2(s2 * t3.x - s1 * t4.x, s2 * t3.y - s1 * t4.y);
  v[0] = make_float2(v[0].x + t1.x + t2.x, v[0].y + t1.y + t2.y);
  if constexpr (SIGN < 0) {
    v[1] = make_float2(a.x + b.y, a.y - b.x);
    v[4] = make_float2(a.x - b.y, a.y + b.x);
    v[2] = make_float2(c.x + d.y, c.y - d.x);
    v[3] = make_float2(c.x - d.y, c.y + d.x);
  } else {
    v[1] = make_float2(a.x - b.y, a.y + b.x);
    v[4] = make_float2(a.x + b.y, a.y - b.x);
    v[2] = make_float2(c.x - d.y, c.y + d.x);
    v[3] = make_float2(c.x + d.y, c.y - d.x);
  }
}

template <int R>
__device__ __forceinline__ void twchain(float2* v, float2 t1) {
  float2 t = t1;
  v[1] = cmulf(v[1], t);
#pragma unroll
  for (int r = 2; r < R; ++r) { t = cmulf(t, t1); v[r] = cmulf(v[r], t); }
}

__device__ __forceinline__ int rev3_5(int q) {
  int q5 = q / 5, q25 = q / 25;
  int d0 = q - 5 * q5, d1 = q5 - 5 * q25;
  return 25 * d0 + 5 * d1 + q25;
}

__device__ __forceinline__ int rev3_4(int q) {
  return ((q & 3) << 4) | (q & 12) | (q >> 4);
}

// ---------- in-place DIF-625 stage, chained twiddles ----------
template <int SUB, int SIGN>
__device__ __forceinline__ void dif5_ip_stage_c(float2* a, int ln) {
  int i1 = ln, i2 = ln + 64;
  bool g2 = (i2 < 125);
  int j1 = i1 % SUB, j2 = i2 % SUB;
  int b1 = (i1 / SUB) * (5 * SUB) + j1;
  int b2 = (i2 / SUB) * (5 * SUB) + j2;
  float2 u[5], v[5];
#pragma unroll
  for (int r = 0; r < 5; ++r) u[r] = a[b1 + SUB * r];
  if (g2) {
#pragma unroll
    for (int r = 0; r < 5; ++r) v[r] = a[b2 + SUB * r];
  }
  bf5s<SIGN>(u);
  twchain<5>(u, cisf((float)SIGN * (TWO_PI / (float)(5 * SUB)) * (float)j1));
  if (g2) {
    bf5s<SIGN>(v);
    twchain<5>(v, cisf((float)SIGN * (TWO_PI / (float)(5 * SUB)) * (float)j2));
  }
#pragma unroll
  for (int r = 0; r < 5; ++r) a[b1 + SUB * r] = u[r];
  if (g2) {
#pragma unroll
    for (int r = 0; r < 5; ++r) a[b2 + SUB * r] = v[r];
  }
}

template <int SUB>
__device__ __forceinline__ void dif5_ip_stage_t(float2* a, int ln, float2 t1a, float2 t1b) {
  int i1 = ln, i2 = ln + 64;
  bool g2 = (i2 < 125);
  int j1 = i1 % SUB, j2 = i2 % SUB;
  int b1 = (i1 / SUB) * (5 * SUB) + j1;
  int b2 = (i2 / SUB) * (5 * SUB) + j2;
  float2 u[5], v[5];
#pragma unroll
  for (int r = 0; r < 5; ++r) u[r] = a[b1 + SUB * r];
  if (g2) {
#pragma unroll
    for (int r = 0; r < 5; ++r) v[r] = a[b2 + SUB * r];
  }
  bf5s<1>(u);
  twchain<5>(u, t1a);
  if (g2) {
    bf5s<1>(v);
    twchain<5>(v, t1b);
  }
#pragma unroll
  for (int r = 0; r < 5; ++r) a[b1 + SUB * r] = u[r];
  if (g2) {
#pragma unroll
    for (int r = 0; r < 5; ++r) a[b2 + SUB * r] = v[r];
  }
}

template <int SIGN>
__device__ __forceinline__ void dif625_ip(float2* a, int ln) {
  dif5_ip_stage_c<125, SIGN>(a, ln);
  dif5_ip_stage_c<25, SIGN>(a, ln);
  dif5_ip_stage_c<5, SIGN>(a, ln);
  int q1 = ln, q2 = ln + 64;
  bool g2 = (q2 < 125);
  float2 u[5], v[5];
#pragma unroll
  for (int r = 0; r < 5; ++r) u[r] = a[5 * q1 + r];
  if (g2) {
#pragma unroll
    for (int r = 0; r < 5; ++r) v[r] = a[5 * q2 + r];
  }
  bf5s<SIGN>(u);
  if (g2) bf5s<SIGN>(v);
  int rv1 = rev3_5(q1), rv2 = rev3_5(q2);
#pragma unroll
  for (int r = 0; r < 5; ++r) a[125 * r + rv1] = u[r];
  if (g2) {
#pragma unroll
    for (int r = 0; r < 5; ++r) a[125 * r + rv2] = v[r];
  }
}

// ---------- in-place DIF-256, pad8-swizzled, chained twiddles ----------
template <int SIGN>
__device__ __forceinline__ void dif256sw_ip(float2* a, int ln) {
  {
    float2 u[4];
#pragma unroll
    for (int r = 0; r < 4; ++r) u[r] = a[pad8(ln + 64 * r)];
    bf4s<SIGN>(u);
    twchain<4>(u, cisf((float)SIGN * (TWO_PI / 256.0f) * (float)ln));
#pragma unroll
    for (int r = 0; r < 4; ++r) a[pad8(ln + 64 * r)] = u[r];
  }
  {
    int j = ln & 15, b = 64 * (ln >> 4) + j;
    float2 u[4];
#pragma unroll
    for (int r = 0; r < 4; ++r) u[r] = a[pad8(b + 16 * r)];
    bf4s<SIGN>(u);
    twchain<4>(u, cisf((float)SIGN * (TWO_PI / 64.0f) * (float)j));
#pragma unroll
    for (int r = 0; r < 4; ++r) a[pad8(b + 16 * r)] = u[r];
  }
  {
    int j = ln & 3, b = 16 * (ln >> 2) + j;
    float2 u[4];
#pragma unroll
    for (int r = 0; r < 4; ++r) u[r] = a[pad8(b + 4 * r)];
    bf4s<SIGN>(u);
    twchain<4>(u, cisf((float)SIGN * (TWO_PI / 16.0f) * (float)j));
#pragma unroll
    for (int r = 0; r < 4; ++r) a[pad8(b + 4 * r)] = u[r];
  }
  {
    float2 u[4];
#pragma unroll
    for (int r = 0; r < 4; ++r) u[r] = a[pad8(4 * ln + r)];
    bf4s<SIGN>(u);
    int rv = rev3_4(ln);
#pragma unroll
    for (int r = 0; r < 4; ++r) a[pad8(64 * r + rv)] = u[r];
  }
}

// ---------- F1: float4 pack, in-place DIF-625 (chained), chained epilogue; zero E ----------
__global__ __launch_bounds__(256) void f1_kernel(const float* __restrict__ win,
                                                 const float* __restrict__ oin,
                                                 float2* __restrict__ G,
                                                 float* __restrict__ E) {
  __shared__ float2 A[4 * 625];    // 20 KB
  int blk = blockIdx.x;
  int gid = blk * 256 + threadIdx.x;
  if (gid < 2 * BATCH * NB * NHOPS) E[gid] = 0.0f;   // replaces memset launch
  int sig = blk >> 6, g = blk & 63;
  int n1base = g * 4;
  int tid = threadIdx.x;
  const float4* wp4 = (const float4*)(win + (size_t)sig * L);
  const float4* op4 = (const float4*)(oin + (size_t)sig * L);
  for (int r = tid; r < 625; r += 256) {
    float4 wv = wp4[r * 64 + g];
    float4 ov = op4[r * 64 + g];
    A[0 * 625 + r] = make_float2(wv.x, ov.x);
    A[1 * 625 + r] = make_float2(wv.y, ov.y);
    A[2 * 625 + r] = make_float2(wv.z, ov.z);
    A[3 * 625 + r] = make_float2(wv.w, ov.w);
  }
  __syncthreads();
  int wv_ = tid >> 6, ln = tid & 63;
  dif625_ip<-1>(A + wv_ * 625, ln);   // barrier-free; natural order out
  __syncthreads();
  // chained epilogue: cc fixed, k2 steps by 64
  int cc = tid & 3, k20 = tid >> 2;
  int n1 = n1base + cc;
  float w = -(TWO_PI / (float)L) * (float)n1;
  float2 t = cisf(w * (float)k20);
  float2 stp = cisf(w * 64.0f);
  for (int k2 = k20; k2 < 625; k2 += 64) {
    G[(size_t)sig * L + k2 * 256 + n1] = cmulf(A[cc * 625 + k2], t);
    t = cmulf(t, stp);
  }
}

// ---------- FI: fused f2+i1. Per wave: forward DIF-256 of one k2-row into LDS;
//              per band: LDS-local masked copy -> inverse DIF-256 ->
//              block-transposed chained epilogue -> coalesced fp16 H (1/L). ----------
__global__ __launch_bounds__(256) void fi_kernel(const float2* __restrict__ G,
                                                 __half2* __restrict__ H) {
  __shared__ float2 Xb[4 * RS];   // forward spectra, natural k1 order (pad8)
  __shared__ float2 Wb[4 * RS];   // per-band inverse work buffers
  int blk = blockIdx.x;
  int sig = blk / 157, gr = blk % 157;
  int k2base = gr * 4;
  int tid = threadIdx.x;
  int wv = tid >> 6, ln = tid & 63;
  int k2 = k2base + wv;
  bool act = (k2 < 625);
  float2* xr = Xb + wv * RS;
  float2* wr = Wb + wv * RS;
  if (act) {
#pragma unroll
    for (int r = 0; r < 4; ++r)
      xr[pad8(ln + 64 * r)] = G[(size_t)sig * L + k2 * 256 + ln + 64 * r];
    dif256sw_ip<-1>(xr, ln);     // forward; barrier-free, wave-local
  }
  // epilogue twiddles are band-independent: hoist out of the band loop
  int cc = tid & 3, n1g = tid >> 2;
  int k2e = k2base + cc;
  float a0 = (TWO_PI / (float)L) * (float)k2e;
  float2 t0 = cisf(a0 * (float)n1g);
  float2 stp = cisf(a0 * 64.0f);
  float2 zero = make_float2(0.0f, 0.0f);

  for (int band = 0; band < NB; ++band) {
    int lo1, hi1, lo2, hi2;
    if (band < 7) {
      lo1 = 10000 * band + 1;        hi1 = 10000 * (band + 1);
      lo2 = L - 10000 * (band + 1);  hi2 = L - 10000 * band - 1;
    } else {
      lo1 = 70001; hi1 = 80000; lo2 = 80001; hi2 = 89999;
    }
    if (act) {
      for (int k1 = ln; k1 < 256; k1 += 64) wr[pad8(k1)] = zero;  // wave-local, in-order
      int s1 = (lo1 - k2 + 624) / 625;
      int e1 = (hi1 - k2) / 625; if (e1 > 255) e1 = 255;
      int s2 = (lo2 - k2 + 624) / 625;
      int e2 = (hi2 - k2) / 625; if (e2 > 255) e2 = 255;
      int c1 = e1 - s1 + 1;
      int c2 = e2 - s2 + 1;
      if (ln < c1) { int k1 = s1 + ln; wr[pad8(k1)] = xr[pad8(k1)]; }
      int l2 = ln - 32;
      if (l2 >= 0 && l2 < c2) { int k1 = s2 + l2; wr[pad8(k1)] = xr[pad8(k1)]; }
      if (band == 7 && k2 == 0 && ln == 0) wr[pad8(0)] = xr[pad8(0)];  // DC -> band 7
      dif256sw_ip<1>(wr, ln);    // inverse; barrier-free, natural order out
    }
    __syncthreads();
    if (k2e < 625) {
      size_t obase = (size_t)(sig * NB + band) * L;
      float2 t = t0;
#pragma unroll
      for (int it = 0; it < 4; ++it) {
        int n1 = n1g + 64 * it;
        float2 val = cmulf(Wb[cc * RS + pad8(n1)], t);
        H[obase + (size_t)n1 * 625 + k2e] = __floats2half2_rn(val.x * INVL, val.y * INVL);
        t = cmulf(t, stp);
      }
    }
    __syncthreads();
  }
}

// ---------- I2: one wave per column, 2 fp16 columns prefetched, cached twiddles,
//              per-wave LDS partials, single barrier ----------
__global__ __launch_bounds__(256) void i2_kernel(const __half2* __restrict__ H,
                                                 float* __restrict__ E) {
  __shared__ float2 A[4 * 625];       // 20000 B
  __shared__ float P[4 * 2 * NHOPS];  // 4992 B
  int blk = blockIdx.x;               // grid = BATCH*NB*32 = 2048
  int g = blk & 31, sb = blk >> 5;
  int band = sb & 7, sig = sb >> 3;
  int tid = threadIdx.x;
  int wv = tid >> 6, ln = tid & 63;
  size_t base = (size_t)(sig * NB + band) * L;
  int n1A = 8 * g + wv, n1B = 8 * g + 4 + wv;
  const __half2* HA = H + base + (size_t)n1A * 625;
  const __half2* HB = H + base + (size_t)n1B * 625;
  int j1 = ln, j2 = ln + 64;
  bool g2 = (j2 < 125);
  __half2 hA1[5], hA2[5], hB1[5], hB2[5];
#pragma unroll
  for (int r = 0; r < 5; ++r) hA1[r] = HA[j1 + 125 * r];
  if (g2) {
#pragma unroll
    for (int r = 0; r < 5; ++r) hA2[r] = HA[j2 + 125 * r];
  }
#pragma unroll
  for (int r = 0; r < 5; ++r) hB1[r] = HB[j1 + 125 * r];
  if (g2) {
#pragma unroll
    for (int r = 0; r < 5; ++r) hB2[r] = HB[j2 + 125 * r];
  }
  float2 tS1a = cisf((TWO_PI / 625.0f) * (float)j1);
  float2 tS1b = cisf((TWO_PI / 625.0f) * (float)j2);
  float2 tS2a = cisf((TWO_PI / 125.0f) * (float)(j1 % 25));
  float2 tS2b = cisf((TWO_PI / 125.0f) * (float)(j2 % 25));
  float2 tS3a = cisf((TWO_PI / 25.0f) * (float)(j1 % 5));
  float2 tS3b = cisf((TWO_PI / 25.0f) * (float)(j2 % 5));
  float2* a = A + wv * 625;
  float* Pw = P + wv * (2 * NHOPS);

  // ---- column A ----
  {
    float2 u[5];
#pragma unroll
    for (int r = 0; r < 5; ++r) u[r] = __half22float2(hA1[r]);
    bf5s<1>(u);
    twchain<5>(u, tS1a);
#pragma unroll
    for (int r = 0; r < 5; ++r) a[j1 + 125 * r] = u[r];
    if (g2) {
      float2 v[5];
#pragma unroll
      for (int r = 0; r < 5; ++r) v[r] = __half22float2(hA2[r]);
      bf5s<1>(v);
      twchain<5>(v, tS1b);
#pragma unroll
      for (int r = 0; r < 5; ++r) a[j2 + 125 * r] = v[r];
    }
  }
  dif5_ip_stage_t<25>(a, ln, tS2a, tS2b);
  dif5_ip_stage_t<5>(a, ln, tS3a, tS3b);
  {
    float2 u[5], v[5];
#pragma unroll
    for (int r = 0; r < 5; ++r) u[r] = a[5 * j1 + r];
    if (g2) {
#pragma unroll
      for (int r = 0; r < 5; ++r) v[r] = a[5 * j2 + r];
    }
    bf5s<1>(u);
    if (g2) bf5s<1>(v);
    int rv1 = rev3_5(j1), rv2 = rev3_5(j2);
#pragma unroll
    for (int r = 0; r < 5; ++r) a[125 * r + rv1] = u[r];
    if (g2) {
#pragma unroll
      for (int r = 0; r < 5; ++r) a[125 * r + rv2] = v[r];
    }
  }
  for (int h = ln; h < NHOPS; h += 64) {
    float ex = 0.0f, ey = 0.0f;
#pragma unroll
    for (int d = 0; d < 4; ++d) {
      float2 z = a[4 * h + d];
      ex += z.x * z.x;
      ey += z.y * z.y;
    }
    Pw[h] = ex;
    Pw[NHOPS + h] = ey;
  }

  // ---- column B (same twiddles) ----
  {
    float2 u[5];
#pragma unroll
    for (int r = 0; r < 5; ++r) u[r] = __half22float2(hB1[r]);
    bf5s<1>(u);
    twchain<5>(u, tS1a);
#pragma unroll
    for (int r = 0; r < 5; ++r) a[j1 + 125 * r] = u[r];
    if (g2) {
      float2 v[5];
#pragma unroll
      for (int r = 0; r < 5; ++r) v[r] = __half22float2(hB2[r]);
      bf5s<1>(v);
      twchain<5>(v, tS1b);
#pragma unroll
      for (int r = 0; r < 5; ++r) a[j2 + 125 * r] = v[r];
    }
  }
  dif5_ip_stage_t<25>(a, ln, tS2a, tS2b);
  dif5_ip_stage_t<5>(a, ln, tS3a, tS3b);
  {
    float2 u[5], v[5];
#pragma unroll
    for (int r = 0; r < 5; ++r) u[r] = a[5 * j1 + r];
    if (g2) {
#pragma unroll
      for (int r = 0; r < 5; ++r) v[r] = a[5 * j2 + r];
    }
    bf5s<1>(u);
    if (g2) bf5s<1>(v);
    int rv1 = rev3_5(j1), rv2 = rev3_5(j2);
#pragma unroll
    for (int r = 0; r < 5; ++r) a[125 * r + rv1] = u[r];
    if (g2) {
#pragma unroll
      for (int r = 0; r < 5; ++r) a[125 * r + rv2] = v[r];
    }
  }
  for (int h = ln; h < NHOPS; h += 64) {
    float ex = 0.0f, ey = 0.0f;
#pragma unroll
    for (int d = 0; d < 4; ++d) {
      float2 z = a[4 * h + d];
      ex += z.x * z.x;
      ey += z.y * z.y;
    }
    Pw[h] += ex;
    Pw[NHOPS + h] += ey;
  }
  __syncthreads();   // the only block-wide barrier
  int eb = (sig * NB + band) * NHOPS;
  for (int idx = tid; idx < 2 * NHOPS; idx += 256) {
    float v = P[idx] + P[2 * NHOPS + idx] + P[4 * NHOPS + idx] + P[6 * NHOPS + idx];
    int comp = idx / NHOPS, h = idx - comp * NHOPS;
    atomicAdd(&E[comp * (BATCH * NB * NHOPS) + eb + h], v);
  }
}

// ---------- finalize: loudness, diff, softmax (H pre-scaled by 1/L -> SC = 1/2048) ----------
__global__ __launch_bounds__(1024) void finalize_kernel(const float* __restrict__ E,
                                                        float* __restrict__ out) {
  constexpr int ND = BATCH * NB * NCHUNK;  // 9920
  constexpr float SC = 1.0f / 2048.0f;
  __shared__ float diffs[ND];
  __shared__ float sred[1024];
  int tid = threadIdx.x;
  for (int idx = tid; idx < ND; idx += 1024) {
    int sb = idx / NCHUNK;
    int k = idx - sb * NCHUNK;
    float msw = (E[sb * NHOPS + k] + E[sb * NHOPS + k + 1]) * SC;
    float mso = (E[64 * NHOPS + sb * NHOPS + k] + E[64 * NHOPS + sb * NHOPS + k + 1]) * SC;
    float lw = -0.691f + 10.0f * log10f(msw + 1e-12f);
    float lo = -0.691f + 10.0f * log10f(mso + 1e-12f);
    diffs[idx] = lw - lo;
  }
  __syncthreads();
  float mx = -3.4e38f;
  for (int idx = tid; idx < ND; idx += 1024) mx = fmaxf(mx, diffs[idx]);
  sred[tid] = mx;
  __syncthreads();
  for (int s = 512; s > 0; s >>= 1) {
    if (tid < s) sred[tid] = fmaxf(sred[tid], sred[tid + s]);
    __syncthreads();
  }
  float gmax = sred[0];
  __syncthreads();
  float se = 0.0f, swd = 0.0f;
  for (int idx = tid; idx < ND; idx += 1024) {
    float d = diffs[idx];
    float e = expf(d - gmax);
    se += e;
    swd += d * e;
  }
  sred[tid] = se; __syncthreads();
  for (int s = 512; s > 0; s >>= 1) { if (tid < s) sred[tid] += sred[tid + s]; __syncthreads(); }
  float tot = sred[0];
  __syncthreads();
  sred[tid] = swd; __syncthreads();
  for (int s = 512; s > 0; s >>= 1) { if (tid < s) sred[tid] += sred[tid + s]; __syncthreads(); }
  if (tid == 0) out[0] = sred[0] / tot;
}

extern "C" void kernel_launch(void* const* d_in, const int* in_sizes, int n_in,
                              void* d_out, int out_size, void* d_ws, size_t ws_size,
                              hipStream_t stream) {
  (void)in_sizes; (void)n_in; (void)out_size; (void)ws_size;
  char* ws = (char*)d_ws;
  float2*  G = (float2*)ws;                        // 10,240,000 B
  __half2* H = (__half2*)(ws + 10240000);          // 40,960,000 B (fp16)
  float*   E = (float*)(ws + 51200000);            // 79,872 B [2][64][156]
  const float* w = (const float*)d_in[0];
  const float* o = (const float*)d_in[1];

  f1_kernel<<<dim3(BATCH * 64), dim3(256), 0, stream>>>(w, o, G, E);
  fi_kernel<<<dim3(BATCH * 157), dim3(256), 0, stream>>>(G, H);
  i2_kernel<<<dim3(BATCH * NB * 32), dim3(256), 0, stream>>>(H, E);
  finalize_kernel<<<dim3(1), dim3(1024), 0, stream>>>(E, (float*)d_out);
}

// Round 2
// 158.349 us; speedup vs baseline: 1.0193x; 1.0193x over previous
//
#include <hip/hip_runtime.h>
#include <hip/hip_fp16.h>
#include <math.h>

// N = 160000 = 256 * 625; four-step FFT decomposition.
// R17 = R16 with fi_kernel restructured: 1024 threads / 16 k2-rows per block
// (restores the 16-lane = 64B coalesced H write of the old i1), 2 bands per
// block x 4 band-groups -> grid 1280 = exactly 5 blocks/CU (perfect balance,
// 2 resident). Forward DIF-256 recomputed per band-group (G is L3-resident:
// FETCH_SIZE measured 5 MB, so re-reads are ~free).
// f1: pack w+i*o (float4), per-wave in-place DIF-625 (chained twiddles) -> G[k2][n1];
//     zeroes E. Epilogue twiddle chained over k2 steps of 64.
// fi: per-wave forward DIF-256 (pad8) of G-row; per band: masked LDS copy,
//     inverse DIF-256, block-transposed chained epilogue -> fp16 H[n1][k2] (1/L).
// i2: one wave per column, 2 fp16 columns prefetched, cached stage twiddles,
//     per-wave LDS partials, single barrier.
constexpr int L      = 160000;
constexpr int BATCH  = 8;
constexpr int NB     = 8;
constexpr int NHOPS  = 156;
constexpr int NCHUNK = 155;
constexpr int RS     = 289;   // swizzled row stride
constexpr float TWO_PI = 6.28318530717958647692f;
constexpr float INVL = 1.0f / (float)L;

__device__ __forceinline__ float2 cmulf(float2 a, float2 b) {
  return make_float2(a.x * b.x - a.y * b.y, a.x * b.y + a.y * b.x);
}

__device__ __forceinline__ float2 cisf(float a) {
  float s, c;
  __sincosf(a, &s, &c);
  return make_float2(c, s);
}

__device__ __forceinline__ int pad8(int i) { return i + (i >> 3); }

template <int SIGN>
__device__ __forceinline__ void bf4s(float2* v) {
  float2 t0 = make_float2(v[0].x + v[2].x, v[0].y + v[2].y);
  float2 t1 = make_float2(v[0].x - v[2].x, v[0].y - v[2].y);
  float2 t2 = make_float2(v[1].x + v[3].x, v[1].y + v[3].y);
  float2 t3 = make_float2(v[1].x - v[3].x, v[1].y - v[3].y);
  v[0] = make_float2(t0.x + t2.x, t0.y + t2.y);
  v[2] = make_float2(t0.x - t2.x, t0.y - t2.y);
  if constexpr (SIGN < 0) {
    v[1] = make_float2(t1.x + t3.y, t1.y - t3.x);
    v[3] = make_float2(t1.x - t3.y, t1.y + t3.x);
  } else {
    v[1] = make_float2(t1.x - t3.y, t1.y + t3.x);
    v[3] = make_float2(t1.x + t3.y, t1.y - t3.x);
  }
}

template <int SIGN>
__device__ __forceinline__ void bf5s(float2* v) {
  const float c1 = 0.30901699437494745f, s1 = 0.9510565162951535f;
  const float c2 = -0.8090169943749475f, s2 = 0.5877852522924731f;
  float2 t1 = make_float2(v[1].x + v[4].x, v[1].y + v[4].y);
  float2 t3 = make_float2(v[1].x - v[4].x, v[1].y - v[4].y);
  float2 t2 = make_float2(v[2].x + v[3].x, v[2].y + v[3].y);
  float2 t4 = make_float2(v[2].x - v[3].x, v[2].y - v[3].y);
  float2 a = make_float2(v[0].x + c1 * t1.x + c2 * t2.x, v[0].y + c1 * t1.y + c2 * t2.y);
  float2 b = make_float2(s1 * t3.x + s2 * t4.x, s1 * t3.y + s2 * t4.y);
  float2 c = make_float2(v[0].x + c2 * t1.x + c1 * t2.x, v[0].y + c2 * t1.y + c1 * t2.y);
  float2 d = make_float2(s2 * t3.x - s1 * t4.x, s2 * t3.y - s1 * t4.y);
  v[0] = make_float2(v[0].x + t1.x + t2.x, v[0].y + t1.y + t2.y);
  if constexpr (SIGN < 0) {
    v[1] = make_float2(a.x + b.y, a.y - b.x);
    v[4] = make_float2(a.x - b.y, a.y + b.x);
    v[2] = make_float2(c.x + d.y, c.y - d.x);
    v[3] = make_float2(c.x - d.y, c.y + d.x);
  } else {
    v[1] = make_float2(a.x - b.y, a.y + b.x);
    v[4] = make_float2(a.x + b.y, a.y - b.x);
    v[2] = make_float2(c.x - d.y, c.y + d.x);
    v[3] = make_float2(c.x + d.y, c.y - d.x);
  }
}

template <int R>
__device__ __forceinline__ void twchain(float2* v, float2 t1) {
  float2 t = t1;
  v[1] = cmulf(v[1], t);
#pragma unroll
  for (int r = 2; r < R; ++r) { t = cmulf(t, t1); v[r] = cmulf(v[r], t); }
}

__device__ __forceinline__ int rev3_5(int q) {
  int q5 = q / 5, q25 = q / 25;
  int d0 = q - 5 * q5, d1 = q5 - 5 * q25;
  return 25 * d0 + 5 * d1 + q25;
}

__device__ __forceinline__ int rev3_4(int q) {
  return ((q & 3) << 4) | (q & 12) | (q >> 4);
}

// ---------- in-place DIF-625 stage, chained twiddles ----------
template <int SUB, int SIGN>
__device__ __forceinline__ void dif5_ip_stage_c(float2* a, int ln) {
  int i1 = ln, i2 = ln + 64;
  bool g2 = (i2 < 125);
  int j1 = i1 % SUB, j2 = i2 % SUB;
  int b1 = (i1 / SUB) * (5 * SUB) + j1;
  int b2 = (i2 / SUB) * (5 * SUB) + j2;
  float2 u[5], v[5];
#pragma unroll
  for (int r = 0; r < 5; ++r) u[r] = a[b1 + SUB * r];
  if (g2) {
#pragma unroll
    for (int r = 0; r < 5; ++r) v[r] = a[b2 + SUB * r];
  }
  bf5s<SIGN>(u);
  twchain<5>(u, cisf((float)SIGN * (TWO_PI / (float)(5 * SUB)) * (float)j1));
  if (g2) {
    bf5s<SIGN>(v);
    twchain<5>(v, cisf((float)SIGN * (TWO_PI / (float)(5 * SUB)) * (float)j2));
  }
#pragma unroll
  for (int r = 0; r < 5; ++r) a[b1 + SUB * r] = u[r];
  if (g2) {
#pragma unroll
    for (int r = 0; r < 5; ++r) a[b2 + SUB * r] = v[r];
  }
}

template <int SUB>
__device__ __forceinline__ void dif5_ip_stage_t(float2* a, int ln, float2 t1a, float2 t1b) {
  int i1 = ln, i2 = ln + 64;
  bool g2 = (i2 < 125);
  int j1 = i1 % SUB, j2 = i2 % SUB;
  int b1 = (i1 / SUB) * (5 * SUB) + j1;
  int b2 = (i2 / SUB) * (5 * SUB) + j2;
  float2 u[5], v[5];
#pragma unroll
  for (int r = 0; r < 5; ++r) u[r] = a[b1 + SUB * r];
  if (g2) {
#pragma unroll
    for (int r = 0; r < 5; ++r) v[r] = a[b2 + SUB * r];
  }
  bf5s<1>(u);
  twchain<5>(u, t1a);
  if (g2) {
    bf5s<1>(v);
    twchain<5>(v, t1b);
  }
#pragma unroll
  for (int r = 0; r < 5; ++r) a[b1 + SUB * r] = u[r];
  if (g2) {
#pragma unroll
    for (int r = 0; r < 5; ++r) a[b2 + SUB * r] = v[r];
  }
}

template <int SIGN>
__device__ __forceinline__ void dif625_ip(float2* a, int ln) {
  dif5_ip_stage_c<125, SIGN>(a, ln);
  dif5_ip_stage_c<25, SIGN>(a, ln);
  dif5_ip_stage_c<5, SIGN>(a, ln);
  int q1 = ln, q2 = ln + 64;
  bool g2 = (q2 < 125);
  float2 u[5], v[5];
#pragma unroll
  for (int r = 0; r < 5; ++r) u[r] = a[5 * q1 + r];
  if (g2) {
#pragma unroll
    for (int r = 0; r < 5; ++r) v[r] = a[5 * q2 + r];
  }
  bf5s<SIGN>(u);
  if (g2) bf5s<SIGN>(v);
  int rv1 = rev3_5(q1), rv2 = rev3_5(q2);
#pragma unroll
  for (int r = 0; r < 5; ++r) a[125 * r + rv1] = u[r];
  if (g2) {
#pragma unroll
    for (int r = 0; r < 5; ++r) a[125 * r + rv2] = v[r];
  }
}

// ---------- in-place DIF-256, pad8-swizzled, chained twiddles ----------
template <int SIGN>
__device__ __forceinline__ void dif256sw_ip(float2* a, int ln) {
  {
    float2 u[4];
#pragma unroll
    for (int r = 0; r < 4; ++r) u[r] = a[pad8(ln + 64 * r)];
    bf4s<SIGN>(u);
    twchain<4>(u, cisf((float)SIGN * (TWO_PI / 256.0f) * (float)ln));
#pragma unroll
    for (int r = 0; r < 4; ++r) a[pad8(ln + 64 * r)] = u[r];
  }
  {
    int j = ln & 15, b = 64 * (ln >> 4) + j;
    float2 u[4];
#pragma unroll
    for (int r = 0; r < 4; ++r) u[r] = a[pad8(b + 16 * r)];
    bf4s<SIGN>(u);
    twchain<4>(u, cisf((float)SIGN * (TWO_PI / 64.0f) * (float)j));
#pragma unroll
    for (int r = 0; r < 4; ++r) a[pad8(b + 16 * r)] = u[r];
  }
  {
    int j = ln & 3, b = 16 * (ln >> 2) + j;
    float2 u[4];
#pragma unroll
    for (int r = 0; r < 4; ++r) u[r] = a[pad8(b + 4 * r)];
    bf4s<SIGN>(u);
    twchain<4>(u, cisf((float)SIGN * (TWO_PI / 16.0f) * (float)j));
#pragma unroll
    for (int r = 0; r < 4; ++r) a[pad8(b + 4 * r)] = u[r];
  }
  {
    float2 u[4];
#pragma unroll
    for (int r = 0; r < 4; ++r) u[r] = a[pad8(4 * ln + r)];
    bf4s<SIGN>(u);
    int rv = rev3_4(ln);
#pragma unroll
    for (int r = 0; r < 4; ++r) a[pad8(64 * r + rv)] = u[r];
  }
}

// ---------- F1: float4 pack, in-place DIF-625 (chained), chained epilogue; zero E ----------
__global__ __launch_bounds__(256) void f1_kernel(const float* __restrict__ win,
                                                 const float* __restrict__ oin,
                                                 float2* __restrict__ G,
                                                 float* __restrict__ E) {
  __shared__ float2 A[4 * 625];    // 20 KB
  int blk = blockIdx.x;
  int gid = blk * 256 + threadIdx.x;
  if (gid < 2 * BATCH * NB * NHOPS) E[gid] = 0.0f;   // replaces memset launch
  int sig = blk >> 6, g = blk & 63;
  int n1base = g * 4;
  int tid = threadIdx.x;
  const float4* wp4 = (const float4*)(win + (size_t)sig * L);
  const float4* op4 = (const float4*)(oin + (size_t)sig * L);
  for (int r = tid; r < 625; r += 256) {
    float4 wv = wp4[r * 64 + g];
    float4 ov = op4[r * 64 + g];
    A[0 * 625 + r] = make_float2(wv.x, ov.x);
    A[1 * 625 + r] = make_float2(wv.y, ov.y);
    A[2 * 625 + r] = make_float2(wv.z, ov.z);
    A[3 * 625 + r] = make_float2(wv.w, ov.w);
  }
  __syncthreads();
  int wv_ = tid >> 6, ln = tid & 63;
  dif625_ip<-1>(A + wv_ * 625, ln);   // barrier-free; natural order out
  __syncthreads();
  // chained epilogue: cc fixed, k2 steps by 64
  int cc = tid & 3, k20 = tid >> 2;
  int n1 = n1base + cc;
  float w = -(TWO_PI / (float)L) * (float)n1;
  float2 t = cisf(w * (float)k20);
  float2 stp = cisf(w * 64.0f);
  for (int k2 = k20; k2 < 625; k2 += 64) {
    G[(size_t)sig * L + k2 * 256 + n1] = cmulf(A[cc * 625 + k2], t);
    t = cmulf(t, stp);
  }
}

// ---------- FI: fused f2+i1, 16 rows / 1024 thr / 2 bands per block.
//              Per wave: forward DIF-256 of one k2-row into Xb; per band:
//              LDS-local masked copy -> inverse DIF-256 -> chained epilogue
//              -> coalesced (64B) fp16 H writes (1/L). Grid 1280 = 5 blk/CU. ----------
__global__ __launch_bounds__(1024) void fi_kernel(const float2* __restrict__ G,
                                                  __half2* __restrict__ H) {
  __shared__ float2 Xb[16 * RS];   // 36,992 B forward spectra (pad8)
  __shared__ float2 Wb[16 * RS];   // 36,992 B per-band inverse work
  int blk = blockIdx.x;            // grid = 4 * BATCH * 40 = 1280
  int bg  = blk / (BATCH * 40);    // band-group 0..3 (2 bands each)
  int rem = blk - bg * (BATCH * 40);
  int sig = rem / 40, gr = rem % 40;
  int k2base = gr * 16;
  int tid = threadIdx.x;
  int wv = tid >> 6, ln = tid & 63;
  int k2 = k2base + wv;
  bool act = (k2 < 625);
  float2* xr = Xb + wv * RS;
  float2* wr = Wb + wv * RS;
  if (act) {
#pragma unroll
    for (int r = 0; r < 4; ++r)
      xr[pad8(ln + 64 * r)] = G[(size_t)sig * L + k2 * 256 + ln + 64 * r];
    dif256sw_ip<-1>(xr, ln);       // forward; barrier-free, wave-local
  }
  // epilogue twiddles are band-independent: hoist out of the band loop
  int cc = tid & 15, n1g = tid >> 4;   // n1g in [0,64)
  int k2e = k2base + cc;
  float a0 = (TWO_PI / (float)L) * (float)k2e;
  float2 t0 = cisf(a0 * (float)n1g);
  float2 stp = cisf(a0 * 64.0f);
  float2 zero = make_float2(0.0f, 0.0f);

#pragma unroll
  for (int bi = 0; bi < 2; ++bi) {
    int band = bg * 2 + bi;
    int lo1, hi1, lo2, hi2;
    if (band < 7) {
      lo1 = 10000 * band + 1;        hi1 = 10000 * (band + 1);
      lo2 = L - 10000 * (band + 1);  hi2 = L - 10000 * band - 1;
    } else {
      lo1 = 70001; hi1 = 80000; lo2 = 80001; hi2 = 89999;
    }
    if (act) {
      for (int k1 = ln; k1 < 256; k1 += 64) wr[pad8(k1)] = zero;  // wave-local, in-order
      int s1 = (lo1 - k2 + 624) / 625;
      int e1 = (hi1 - k2) / 625; if (e1 > 255) e1 = 255;
      int s2 = (lo2 - k2 + 624) / 625;
      int e2 = (hi2 - k2) / 625; if (e2 > 255) e2 = 255;
      int c1 = e1 - s1 + 1;
      int c2 = e2 - s2 + 1;
      if (ln < c1) { int k1 = s1 + ln; wr[pad8(k1)] = xr[pad8(k1)]; }
      int l2 = ln - 32;
      if (l2 >= 0 && l2 < c2) { int k1 = s2 + l2; wr[pad8(k1)] = xr[pad8(k1)]; }
      if (band == 7 && k2 == 0 && ln == 0) wr[pad8(0)] = xr[pad8(0)];  // DC -> band 7
      dif256sw_ip<1>(wr, ln);      // inverse; barrier-free, natural order out
    }
    __syncthreads();
    if (k2e < 625) {
      size_t obase = (size_t)(sig * NB + band) * L;
      float2 t = t0;
#pragma unroll
      for (int it = 0; it < 4; ++it) {
        int n1 = n1g + 64 * it;
        float2 val = cmulf(Wb[cc * RS + pad8(n1)], t);
        H[obase + (size_t)n1 * 625 + k2e] = __floats2half2_rn(val.x * INVL, val.y * INVL);
        t = cmulf(t, stp);
      }
    }
    __syncthreads();
  }
}

// ---------- I2: one wave per column, 2 fp16 columns prefetched, cached twiddles,
//              per-wave LDS partials, single barrier ----------
__global__ __launch_bounds__(256) void i2_kernel(const __half2* __restrict__ H,
                                                 float* __restrict__ E) {
  __shared__ float2 A[4 * 625];       // 20000 B
  __shared__ float P[4 * 2 * NHOPS];  // 4992 B
  int blk = blockIdx.x;               // grid = BATCH*NB*32 = 2048
  int g = blk & 31, sb = blk >> 5;
  int band = sb & 7, sig = sb >> 3;
  int tid = threadIdx.x;
  int wv = tid >> 6, ln = tid & 63;
  size_t base = (size_t)(sig * NB + band) * L;
  int n1A = 8 * g + wv, n1B = 8 * g + 4 + wv;
  const __half2* HA = H + base + (size_t)n1A * 625;
  const __half2* HB = H + base + (size_t)n1B * 625;
  int j1 = ln, j2 = ln + 64;
  bool g2 = (j2 < 125);
  __half2 hA1[5], hA2[5], hB1[5], hB2[5];
#pragma unroll
  for (int r = 0; r < 5; ++r) hA1[r] = HA[j1 + 125 * r];
  if (g2) {
#pragma unroll
    for (int r = 0; r < 5; ++r) hA2[r] = HA[j2 + 125 * r];
  }
#pragma unroll
  for (int r = 0; r < 5; ++r) hB1[r] = HB[j1 + 125 * r];
  if (g2) {
#pragma unroll
    for (int r = 0; r < 5; ++r) hB2[r] = HB[j2 + 125 * r];
  }
  float2 tS1a = cisf((TWO_PI / 625.0f) * (float)j1);
  float2 tS1b = cisf((TWO_PI / 625.0f) * (float)j2);
  float2 tS2a = cisf((TWO_PI / 125.0f) * (float)(j1 % 25));
  float2 tS2b = cisf((TWO_PI / 125.0f) * (float)(j2 % 25));
  float2 tS3a = cisf((TWO_PI / 25.0f) * (float)(j1 % 5));
  float2 tS3b = cisf((TWO_PI / 25.0f) * (float)(j2 % 5));
  float2* a = A + wv * 625;
  float* Pw = P + wv * (2 * NHOPS);

  // ---- column A ----
  {
    float2 u[5];
#pragma unroll
    for (int r = 0; r < 5; ++r) u[r] = __half22float2(hA1[r]);
    bf5s<1>(u);
    twchain<5>(u, tS1a);
#pragma unroll
    for (int r = 0; r < 5; ++r) a[j1 + 125 * r] = u[r];
    if (g2) {
      float2 v[5];
#pragma unroll
      for (int r = 0; r < 5; ++r) v[r] = __half22float2(hA2[r]);
      bf5s<1>(v);
      twchain<5>(v, tS1b);
#pragma unroll
      for (int r = 0; r < 5; ++r) a[j2 + 125 * r] = v[r];
    }
  }
  dif5_ip_stage_t<25>(a, ln, tS2a, tS2b);
  dif5_ip_stage_t<5>(a, ln, tS3a, tS3b);
  {
    float2 u[5], v[5];
#pragma unroll
    for (int r = 0; r < 5; ++r) u[r] = a[5 * j1 + r];
    if (g2) {
#pragma unroll
      for (int r = 0; r < 5; ++r) v[r] = a[5 * j2 + r];
    }
    bf5s<1>(u);
    if (g2) bf5s<1>(v);
    int rv1 = rev3_5(j1), rv2 = rev3_5(j2);
#pragma unroll
    for (int r = 0; r < 5; ++r) a[125 * r + rv1] = u[r];
    if (g2) {
#pragma unroll
      for (int r = 0; r < 5; ++r) a[125 * r + rv2] = v[r];
    }
  }
  for (int h = ln; h < NHOPS; h += 64) {
    float ex = 0.0f, ey = 0.0f;
#pragma unroll
    for (int d = 0; d < 4; ++d) {
      float2 z = a[4 * h + d];
      ex += z.x * z.x;
      ey += z.y * z.y;
    }
    Pw[h] = ex;
    Pw[NHOPS + h] = ey;
  }

  // ---- column B (same twiddles) ----
  {
    float2 u[5];
#pragma unroll
    for (int r = 0; r < 5; ++r) u[r] = __half22float2(hB1[r]);
    bf5s<1>(u);
    twchain<5>(u, tS1a);
#pragma unroll
    for (int r = 0; r < 5; ++r) a[j1 + 125 * r] = u[r];
    if (g2) {
      float2 v[5];
#pragma unroll
      for (int r = 0; r < 5; ++r) v[r] = __half22float2(hB2[r]);
      bf5s<1>(v);
      twchain<5>(v, tS1b);
#pragma unroll
      for (int r = 0; r < 5; ++r) a[j2 + 125 * r] = v[r];
    }
  }
  dif5_ip_stage_t<25>(a, ln, tS2a, tS2b);
  dif5_ip_stage_t<5>(a, ln, tS3a, tS3b);
  {
    float2 u[5], v[5];
#pragma unroll
    for (int r = 0; r < 5; ++r) u[r] = a[5 * j1 + r];
    if (g2) {
#pragma unroll
      for (int r = 0; r < 5; ++r) v[r] = a[5 * j2 + r];
    }
    bf5s<1>(u);
    if (g2) bf5s<1>(v);
    int rv1 = rev3_5(j1), rv2 = rev3_5(j2);
#pragma unroll
    for (int r = 0; r < 5; ++r) a[125 * r + rv1] = u[r];
    if (g2) {
#pragma unroll
      for (int r = 0; r < 5; ++r) a[125 * r + rv2] = v[r];
    }
  }
  for (int h = ln; h < NHOPS; h += 64) {
    float ex = 0.0f, ey = 0.0f;
#pragma unroll
    for (int d = 0; d < 4; ++d) {
      float2 z = a[4 * h + d];
      ex += z.x * z.x;
      ey += z.y * z.y;
    }
    Pw[h] += ex;
    Pw[NHOPS + h] += ey;
  }
  __syncthreads();   // the only block-wide barrier
  int eb = (sig * NB + band) * NHOPS;
  for (int idx = tid; idx < 2 * NHOPS; idx += 256) {
    float v = P[idx] + P[2 * NHOPS + idx] + P[4 * NHOPS + idx] + P[6 * NHOPS + idx];
    int comp = idx / NHOPS, h = idx - comp * NHOPS;
    atomicAdd(&E[comp * (BATCH * NB * NHOPS) + eb + h], v);
  }
}

// ---------- finalize: loudness, diff, softmax (H pre-scaled by 1/L -> SC = 1/2048) ----------
__global__ __launch_bounds__(1024) void finalize_kernel(const float* __restrict__ E,
                                                        float* __restrict__ out) {
  constexpr int ND = BATCH * NB * NCHUNK;  // 9920
  constexpr float SC = 1.0f / 2048.0f;
  __shared__ float diffs[ND];
  __shared__ float sred[1024];
  int tid = threadIdx.x;
  for (int idx = tid; idx < ND; idx += 1024) {
    int sb = idx / NCHUNK;
    int k = idx - sb * NCHUNK;
    float msw = (E[sb * NHOPS + k] + E[sb * NHOPS + k + 1]) * SC;
    float mso = (E[64 * NHOPS + sb * NHOPS + k] + E[64 * NHOPS + sb * NHOPS + k + 1]) * SC;
    float lw = -0.691f + 10.0f * log10f(msw + 1e-12f);
    float lo = -0.691f + 10.0f * log10f(mso + 1e-12f);
    diffs[idx] = lw - lo;
  }
  __syncthreads();
  float mx = -3.4e38f;
  for (int idx = tid; idx < ND; idx += 1024) mx = fmaxf(mx, diffs[idx]);
  sred[tid] = mx;
  __syncthreads();
  for (int s = 512; s > 0; s >>= 1) {
    if (tid < s) sred[tid] = fmaxf(sred[tid], sred[tid + s]);
    __syncthreads();
  }
  float gmax = sred[0];
  __syncthreads();
  float se = 0.0f, swd = 0.0f;
  for (int idx = tid; idx < ND; idx += 1024) {
    float d = diffs[idx];
    float e = expf(d - gmax);
    se += e;
    swd += d * e;
  }
  sred[tid] = se; __syncthreads();
  for (int s = 512; s > 0; s >>= 1) { if (tid < s) sred[tid] += sred[tid + s]; __syncthreads(); }
  float tot = sred[0];
  __syncthreads();
  sred[tid] = swd; __syncthreads();
  for (int s = 512; s > 0; s >>= 1) { if (tid < s) sred[tid] += sred[tid + s]; __syncthreads(); }
  if (tid == 0) out[0] = sred[0] / tot;
}

extern "C" void kernel_launch(void* const* d_in, const int* in_sizes, int n_in,
                              void* d_out, int out_size, void* d_ws, size_t ws_size,
                              hipStream_t stream) {
  (void)in_sizes; (void)n_in; (void)out_size; (void)ws_size;
  char* ws = (char*)d_ws;
  float2*  G = (float2*)ws;                        // 10,240,000 B
  __half2* H = (__half2*)(ws + 10240000);          // 40,960,000 B (fp16)
  float*   E = (float*)(ws + 51200000);            // 79,872 B [2][64][156]
  const float* w = (const float*)d_in[0];
  const float* o = (const float*)d_in[1];

  f1_kernel<<<dim3(BATCH * 64), dim3(256), 0, stream>>>(w, o, G, E);
  fi_kernel<<<dim3(4 * BATCH * 40), dim3(1024), 0, stream>>>(G, H);
  i2_kernel<<<dim3(BATCH * NB * 32), dim3(256), 0, stream>>>(H, E);
  finalize_kernel<<<dim3(1), dim3(1024), 0, stream>>>(E, (float*)d_out);
}

// Round 3
// 144.122 us; speedup vs baseline: 1.1199x; 1.0987x over previous
//
#include <hip/hip_runtime.h>
#include <hip/hip_fp16.h>
#include <math.h>

// N = 160000 = 256 * 625; four-step FFT decomposition.
// R18 = R17 with fi_kernel de-fattened:
//  - stage twiddles (tw1..3) hoisted out of the band loop; forward uses their
//    conjugates (sign flip is free) -> 11 sincos/lane -> 5.
//  - band mask fused into inverse stage 1 as an in-register predicate on
//    k = 625*k1 + k2 (replaces zero-fill + masked copy + 4 int divides/band).
//  - inverse stage 4 fused into the epilogue: thread (cc,q) reads the four
//    stage-3 values of butterfly q (base + r, conflict-free quarters), bf4 in
//    registers, chained twiddle, writes H directly. Removes the 4-way
//    conflicted stage-4 round trip AND the 4-way conflicted epilogue read.
// f1: pack w+i*o (float4), per-wave in-place DIF-625 (chained twiddles) -> G[k2][n1].
// i2: one wave per column, 2 fp16 columns prefetched, cached stage twiddles,
//     per-wave LDS partials, single barrier.
constexpr int L      = 160000;
constexpr int BATCH  = 8;
constexpr int NB     = 8;
constexpr int NHOPS  = 156;
constexpr int NCHUNK = 155;
constexpr int RS     = 289;   // swizzled row stride
constexpr float TWO_PI = 6.28318530717958647692f;
constexpr float INVL = 1.0f / (float)L;

__device__ __forceinline__ float2 cmulf(float2 a, float2 b) {
  return make_float2(a.x * b.x - a.y * b.y, a.x * b.y + a.y * b.x);
}

__device__ __forceinline__ float2 cisf(float a) {
  float s, c;
  __sincosf(a, &s, &c);
  return make_float2(c, s);
}

__device__ __forceinline__ float2 conjf(float2 a) { return make_float2(a.x, -a.y); }

__device__ __forceinline__ int pad8(int i) { return i + (i >> 3); }

template <int SIGN>
__device__ __forceinline__ void bf4s(float2* v) {
  float2 t0 = make_float2(v[0].x + v[2].x, v[0].y + v[2].y);
  float2 t1 = make_float2(v[0].x - v[2].x, v[0].y - v[2].y);
  float2 t2 = make_float2(v[1].x + v[3].x, v[1].y + v[3].y);
  float2 t3 = make_float2(v[1].x - v[3].x, v[1].y - v[3].y);
  v[0] = make_float2(t0.x + t2.x, t0.y + t2.y);
  v[2] = make_float2(t0.x - t2.x, t0.y - t2.y);
  if constexpr (SIGN < 0) {
    v[1] = make_float2(t1.x + t3.y, t1.y - t3.x);
    v[3] = make_float2(t1.x - t3.y, t1.y + t3.x);
  } else {
    v[1] = make_float2(t1.x - t3.y, t1.y + t3.x);
    v[3] = make_float2(t1.x + t3.y, t1.y - t3.x);
  }
}

template <int SIGN>
__device__ __forceinline__ void bf5s(float2* v) {
  const float c1 = 0.30901699437494745f, s1 = 0.9510565162951535f;
  const float c2 = -0.8090169943749475f, s2 = 0.5877852522924731f;
  float2 t1 = make_float2(v[1].x + v[4].x, v[1].y + v[4].y);
  float2 t3 = make_float2(v[1].x - v[4].x, v[1].y - v[4].y);
  float2 t2 = make_float2(v[2].x + v[3].x, v[2].y + v[3].y);
  float2 t4 = make_float2(v[2].x - v[3].x, v[2].y - v[3].y);
  float2 a = make_float2(v[0].x + c1 * t1.x + c2 * t2.x, v[0].y + c1 * t1.y + c2 * t2.y);
  float2 b = make_float2(s1 * t3.x + s2 * t4.x, s1 * t3.y + s2 * t4.y);
  float2 c = make_float2(v[0].x + c2 * t1.x + c1 * t2.x, v[0].y + c2 * t1.y + c1 * t2.y);
  float2 d = make_float2(s2 * t3.x - s1 * t4.x, s2 * t3.y - s1 * t4.y);
  v[0] = make_float2(v[0].x + t1.x + t2.x, v[0].y + t1.y + t2.y);
  if constexpr (SIGN < 0) {
    v[1] = make_float2(a.x + b.y, a.y - b.x);
    v[4] = make_float2(a.x - b.y, a.y + b.x);
    v[2] = make_float2(c.x + d.y, c.y - d.x);
    v[3] = make_float2(c.x - d.y, c.y + d.x);
  } else {
    v[1] = make_float2(a.x - b.y, a.y + b.x);
    v[4] = make_float2(a.x + b.y, a.y - b.x);
    v[2] = make_float2(c.x - d.y, c.y + d.x);
    v[3] = make_float2(c.x + d.y, c.y - d.x);
  }
}

template <int R>
__device__ __forceinline__ void twchain(float2* v, float2 t1) {
  float2 t = t1;
  v[1] = cmulf(v[1], t);
#pragma unroll
  for (int r = 2; r < R; ++r) { t = cmulf(t, t1); v[r] = cmulf(v[r], t); }
}

__device__ __forceinline__ int rev3_5(int q) {
  int q5 = q / 5, q25 = q / 25;
  int d0 = q - 5 * q5, d1 = q5 - 5 * q25;
  return 25 * d0 + 5 * d1 + q25;
}

__device__ __forceinline__ int rev3_4(int q) {
  return ((q & 3) << 4) | (q & 12) | (q >> 4);
}

// ---------- in-place DIF-625 stage, chained twiddles ----------
template <int SUB, int SIGN>
__device__ __forceinline__ void dif5_ip_stage_c(float2* a, int ln) {
  int i1 = ln, i2 = ln + 64;
  bool g2 = (i2 < 125);
  int j1 = i1 % SUB, j2 = i2 % SUB;
  int b1 = (i1 / SUB) * (5 * SUB) + j1;
  int b2 = (i2 / SUB) * (5 * SUB) + j2;
  float2 u[5], v[5];
#pragma unroll
  for (int r = 0; r < 5; ++r) u[r] = a[b1 + SUB * r];
  if (g2) {
#pragma unroll
    for (int r = 0; r < 5; ++r) v[r] = a[b2 + SUB * r];
  }
  bf5s<SIGN>(u);
  twchain<5>(u, cisf((float)SIGN * (TWO_PI / (float)(5 * SUB)) * (float)j1));
  if (g2) {
    bf5s<SIGN>(v);
    twchain<5>(v, cisf((float)SIGN * (TWO_PI / (float)(5 * SUB)) * (float)j2));
  }
#pragma unroll
  for (int r = 0; r < 5; ++r) a[b1 + SUB * r] = u[r];
  if (g2) {
#pragma unroll
    for (int r = 0; r < 5; ++r) a[b2 + SUB * r] = v[r];
  }
}

template <int SUB>
__device__ __forceinline__ void dif5_ip_stage_t(float2* a, int ln, float2 t1a, float2 t1b) {
  int i1 = ln, i2 = ln + 64;
  bool g2 = (i2 < 125);
  int j1 = i1 % SUB, j2 = i2 % SUB;
  int b1 = (i1 / SUB) * (5 * SUB) + j1;
  int b2 = (i2 / SUB) * (5 * SUB) + j2;
  float2 u[5], v[5];
#pragma unroll
  for (int r = 0; r < 5; ++r) u[r] = a[b1 + SUB * r];
  if (g2) {
#pragma unroll
    for (int r = 0; r < 5; ++r) v[r] = a[b2 + SUB * r];
  }
  bf5s<1>(u);
  twchain<5>(u, t1a);
  if (g2) {
    bf5s<1>(v);
    twchain<5>(v, t1b);
  }
#pragma unroll
  for (int r = 0; r < 5; ++r) a[b1 + SUB * r] = u[r];
  if (g2) {
#pragma unroll
    for (int r = 0; r < 5; ++r) a[b2 + SUB * r] = v[r];
  }
}

template <int SIGN>
__device__ __forceinline__ void dif625_ip(float2* a, int ln) {
  dif5_ip_stage_c<125, SIGN>(a, ln);
  dif5_ip_stage_c<25, SIGN>(a, ln);
  dif5_ip_stage_c<5, SIGN>(a, ln);
  int q1 = ln, q2 = ln + 64;
  bool g2 = (q2 < 125);
  float2 u[5], v[5];
#pragma unroll
  for (int r = 0; r < 5; ++r) u[r] = a[5 * q1 + r];
  if (g2) {
#pragma unroll
    for (int r = 0; r < 5; ++r) v[r] = a[5 * q2 + r];
  }
  bf5s<SIGN>(u);
  if (g2) bf5s<SIGN>(v);
  int rv1 = rev3_5(q1), rv2 = rev3_5(q2);
#pragma unroll
  for (int r = 0; r < 5; ++r) a[125 * r + rv1] = u[r];
  if (g2) {
#pragma unroll
    for (int r = 0; r < 5; ++r) a[125 * r + rv2] = v[r];
  }
}

// ---------- in-place DIF-256, pad8-swizzled, hoisted twiddles ----------
// twN must already carry the transform sign (pass conj for forward).
template <int SIGN>
__device__ __forceinline__ void dif256sw_tw(float2* a, int ln,
                                            float2 tw1, float2 tw2, float2 tw3) {
  {
    int b = pad8(ln);            // + 72*r exact
    float2 u[4];
#pragma unroll
    for (int r = 0; r < 4; ++r) u[r] = a[b + 72 * r];
    bf4s<SIGN>(u);
    twchain<4>(u, tw1);
#pragma unroll
    for (int r = 0; r < 4; ++r) a[b + 72 * r] = u[r];
  }
  {
    int j = ln & 15, b = pad8(64 * (ln >> 4) + j);   // + 18*r exact
    float2 u[4];
#pragma unroll
    for (int r = 0; r < 4; ++r) u[r] = a[b + 18 * r];
    bf4s<SIGN>(u);
    twchain<4>(u, tw2);
#pragma unroll
    for (int r = 0; r < 4; ++r) a[b + 18 * r] = u[r];
  }
  {
    int j = ln & 3, jb = 16 * (ln >> 2) + j;
    float2 u[4];
#pragma unroll
    for (int r = 0; r < 4; ++r) u[r] = a[pad8(jb + 4 * r)];
    bf4s<SIGN>(u);
    twchain<4>(u, tw3);
#pragma unroll
    for (int r = 0; r < 4; ++r) a[pad8(jb + 4 * r)] = u[r];
  }
  {
    float2 u[4];
#pragma unroll
    for (int r = 0; r < 4; ++r) u[r] = a[pad8(4 * ln + r)];
    bf4s<SIGN>(u);
    int rv = rev3_4(ln);
#pragma unroll
    for (int r = 0; r < 4; ++r) a[pad8(64 * r + rv)] = u[r];
  }
}

// ---------- F1: float4 pack, in-place DIF-625 (chained), chained epilogue; zero E ----------
__global__ __launch_bounds__(256) void f1_kernel(const float* __restrict__ win,
                                                 const float* __restrict__ oin,
                                                 float2* __restrict__ G,
                                                 float* __restrict__ E) {
  __shared__ float2 A[4 * 625];    // 20 KB
  int blk = blockIdx.x;
  int gid = blk * 256 + threadIdx.x;
  if (gid < 2 * BATCH * NB * NHOPS) E[gid] = 0.0f;   // replaces memset launch
  int sig = blk >> 6, g = blk & 63;
  int n1base = g * 4;
  int tid = threadIdx.x;
  const float4* wp4 = (const float4*)(win + (size_t)sig * L);
  const float4* op4 = (const float4*)(oin + (size_t)sig * L);
  for (int r = tid; r < 625; r += 256) {
    float4 wv = wp4[r * 64 + g];
    float4 ov = op4[r * 64 + g];
    A[0 * 625 + r] = make_float2(wv.x, ov.x);
    A[1 * 625 + r] = make_float2(wv.y, ov.y);
    A[2 * 625 + r] = make_float2(wv.z, ov.z);
    A[3 * 625 + r] = make_float2(wv.w, ov.w);
  }
  __syncthreads();
  int wv_ = tid >> 6, ln = tid & 63;
  dif625_ip<-1>(A + wv_ * 625, ln);   // barrier-free; natural order out
  __syncthreads();
  // chained epilogue: cc fixed, k2 steps by 64
  int cc = tid & 3, k20 = tid >> 2;
  int n1 = n1base + cc;
  float w = -(TWO_PI / (float)L) * (float)n1;
  float2 t = cisf(w * (float)k20);
  float2 stp = cisf(w * 64.0f);
  for (int k2 = k20; k2 < 625; k2 += 64) {
    G[(size_t)sig * L + k2 * 256 + n1] = cmulf(A[cc * 625 + k2], t);
    t = cmulf(t, stp);
  }
}

// ---------- FI: fused f2+i1, 16 rows / 1024 thr / 2 bands per block. ----------
__global__ __launch_bounds__(1024) void fi_kernel(const float2* __restrict__ G,
                                                  __half2* __restrict__ H) {
  __shared__ float2 Xb[16 * RS];   // forward spectra (pad8)
  __shared__ float2 Wb[16 * RS];   // inverse work (stages 1-3)
  int blk = blockIdx.x;            // grid = 4 * BATCH * 40 = 1280
  int bg  = blk / (BATCH * 40);    // band-group 0..3 (2 bands each)
  int rem = blk - bg * (BATCH * 40);
  int sig = rem / 40, gr = rem % 40;
  int k2base = gr * 16;
  int tid = threadIdx.x;
  int wv = tid >> 6, ln = tid & 63;
  int k2 = k2base + wv;
  bool act = (k2 < 625);
  float2* xr = Xb + wv * RS;
  float2* wr = Wb + wv * RS;

  // ---- hoisted stage twiddles (inverse sign; forward uses conj) ----
  float2 tw1 = cisf((TWO_PI / 256.0f) * (float)ln);
  float2 tw2 = cisf((TWO_PI / 64.0f) * (float)(ln & 15));
  float2 tw3 = cisf((TWO_PI / 16.0f) * (float)(ln & 3));

  // ---- forward DIF-256 of own row (once) ----
  if (act) {
#pragma unroll
    for (int r = 0; r < 4; ++r)
      xr[pad8(ln + 64 * r)] = G[(size_t)sig * L + k2 * 256 + ln + 64 * r];
    dif256sw_tw<-1>(xr, ln, conjf(tw1), conjf(tw2), conjf(tw3));
  }

  // ---- hoisted per-lane LDS bases (stage strides are exact in pad8 space) ----
  int b1 = pad8(ln);                              // + 72*r
  int b2 = pad8(64 * (ln >> 4) + (ln & 15));      // + 18*r
  int jb3 = 16 * (ln >> 2) + (ln & 3);            // pad8(jb3 + 4*r)
  int kb = 625 * ln + k2;                         // + 40000*r  (bin number)

  // ---- fused stage-4 + epilogue constants ----
  int cc = tid & 15, q = tid >> 4;                // q in 0..63 (butterfly id)
  int rq = rev3_4(q);                             // n1 = 64*r + rq
  int k2e = k2base + cc;
  bool eact = (k2e < 625);
  float a0 = (TWO_PI / (float)L) * (float)k2e;
  float2 t0q = cisf(a0 * (float)rq);
  float2 stp = cisf(a0 * 64.0f);
  int b4 = cc * RS + pad8(4 * q);                 // + r exact (r<4)

#pragma unroll
  for (int bi = 0; bi < 2; ++bi) {
    int band = bg * 2 + bi;
    unsigned lo1, d1, lo2, d2;
    if (band < 7) {
      lo1 = 10000u * band + 1u;              d1 = 9999u;
      lo2 = (unsigned)L - 10000u * (band + 1); d2 = 9999u;
    } else {
      lo1 = 70001u; d1 = 19998u;             // 70001..89999
      lo2 = 0u;     d2 = 0u;                 // DC bin -> band 7
    }
    if (act) {
      float2 u[4];
      // stage 1: read Xb with in-register band mask, write Wb
#pragma unroll
      for (int r = 0; r < 4; ++r) {
        float2 x = xr[b1 + 72 * r];
        unsigned k = (unsigned)(kb + 40000 * r);
        bool in = ((k - lo1) <= d1) || ((k - lo2) <= d2);
        u[r] = in ? x : make_float2(0.0f, 0.0f);
      }
      bf4s<1>(u);
      twchain<4>(u, tw1);
#pragma unroll
      for (int r = 0; r < 4; ++r) wr[b1 + 72 * r] = u[r];
      // stage 2
#pragma unroll
      for (int r = 0; r < 4; ++r) u[r] = wr[b2 + 18 * r];
      bf4s<1>(u);
      twchain<4>(u, tw2);
#pragma unroll
      for (int r = 0; r < 4; ++r) wr[b2 + 18 * r] = u[r];
      // stage 3
#pragma unroll
      for (int r = 0; r < 4; ++r) u[r] = wr[pad8(jb3 + 4 * r)];
      bf4s<1>(u);
      twchain<4>(u, tw3);
#pragma unroll
      for (int r = 0; r < 4; ++r) wr[pad8(jb3 + 4 * r)] = u[r];
    }
    __syncthreads();
    // fused stage 4 + epilogue: butterfly q of row cc, outputs n1 = 64r + rq
    if (eact) {
      size_t obase = (size_t)(sig * NB + band) * L;
      float2 v[4];
#pragma unroll
      for (int r = 0; r < 4; ++r) v[r] = Wb[b4 + r];
      bf4s<1>(v);
      float2 t = t0q;
#pragma unroll
      for (int r = 0; r < 4; ++r) {
        int n1 = 64 * r + rq;
        float2 val = cmulf(v[r], t);
        H[obase + (size_t)n1 * 625 + k2e] = __floats2half2_rn(val.x * INVL, val.y * INVL);
        t = cmulf(t, stp);
      }
    }
    __syncthreads();
  }
}

// ---------- I2: one wave per column, 2 fp16 columns prefetched, cached twiddles,
//              per-wave LDS partials, single barrier ----------
__global__ __launch_bounds__(256) void i2_kernel(const __half2* __restrict__ H,
                                                 float* __restrict__ E) {
  __shared__ float2 A[4 * 625];       // 20000 B
  __shared__ float P[4 * 2 * NHOPS];  // 4992 B
  int blk = blockIdx.x;               // grid = BATCH*NB*32 = 2048
  int g = blk & 31, sb = blk >> 5;
  int band = sb & 7, sig = sb >> 3;
  int tid = threadIdx.x;
  int wv = tid >> 6, ln = tid & 63;
  size_t base = (size_t)(sig * NB + band) * L;
  int n1A = 8 * g + wv, n1B = 8 * g + 4 + wv;
  const __half2* HA = H + base + (size_t)n1A * 625;
  const __half2* HB = H + base + (size_t)n1B * 625;
  int j1 = ln, j2 = ln + 64;
  bool g2 = (j2 < 125);
  __half2 hA1[5], hA2[5], hB1[5], hB2[5];
#pragma unroll
  for (int r = 0; r < 5; ++r) hA1[r] = HA[j1 + 125 * r];
  if (g2) {
#pragma unroll
    for (int r = 0; r < 5; ++r) hA2[r] = HA[j2 + 125 * r];
  }
#pragma unroll
  for (int r = 0; r < 5; ++r) hB1[r] = HB[j1 + 125 * r];
  if (g2) {
#pragma unroll
    for (int r = 0; r < 5; ++r) hB2[r] = HB[j2 + 125 * r];
  }
  float2 tS1a = cisf((TWO_PI / 625.0f) * (float)j1);
  float2 tS1b = cisf((TWO_PI / 625.0f) * (float)j2);
  float2 tS2a = cisf((TWO_PI / 125.0f) * (float)(j1 % 25));
  float2 tS2b = cisf((TWO_PI / 125.0f) * (float)(j2 % 25));
  float2 tS3a = cisf((TWO_PI / 25.0f) * (float)(j1 % 5));
  float2 tS3b = cisf((TWO_PI / 25.0f) * (float)(j2 % 5));
  float2* a = A + wv * 625;
  float* Pw = P + wv * (2 * NHOPS);

  // ---- column A ----
  {
    float2 u[5];
#pragma unroll
    for (int r = 0; r < 5; ++r) u[r] = __half22float2(hA1[r]);
    bf5s<1>(u);
    twchain<5>(u, tS1a);
#pragma unroll
    for (int r = 0; r < 5; ++r) a[j1 + 125 * r] = u[r];
    if (g2) {
      float2 v[5];
#pragma unroll
      for (int r = 0; r < 5; ++r) v[r] = __half22float2(hA2[r]);
      bf5s<1>(v);
      twchain<5>(v, tS1b);
#pragma unroll
      for (int r = 0; r < 5; ++r) a[j2 + 125 * r] = v[r];
    }
  }
  dif5_ip_stage_t<25>(a, ln, tS2a, tS2b);
  dif5_ip_stage_t<5>(a, ln, tS3a, tS3b);
  {
    float2 u[5], v[5];
#pragma unroll
    for (int r = 0; r < 5; ++r) u[r] = a[5 * j1 + r];
    if (g2) {
#pragma unroll
      for (int r = 0; r < 5; ++r) v[r] = a[5 * j2 + r];
    }
    bf5s<1>(u);
    if (g2) bf5s<1>(v);
    int rv1 = rev3_5(j1), rv2 = rev3_5(j2);
#pragma unroll
    for (int r = 0; r < 5; ++r) a[125 * r + rv1] = u[r];
    if (g2) {
#pragma unroll
      for (int r = 0; r < 5; ++r) a[125 * r + rv2] = v[r];
    }
  }
  for (int h = ln; h < NHOPS; h += 64) {
    float ex = 0.0f, ey = 0.0f;
#pragma unroll
    for (int d = 0; d < 4; ++d) {
      float2 z = a[4 * h + d];
      ex += z.x * z.x;
      ey += z.y * z.y;
    }
    Pw[h] = ex;
    Pw[NHOPS + h] = ey;
  }

  // ---- column B (same twiddles) ----
  {
    float2 u[5];
#pragma unroll
    for (int r = 0; r < 5; ++r) u[r] = __half22float2(hB1[r]);
    bf5s<1>(u);
    twchain<5>(u, tS1a);
#pragma unroll
    for (int r = 0; r < 5; ++r) a[j1 + 125 * r] = u[r];
    if (g2) {
      float2 v[5];
#pragma unroll
      for (int r = 0; r < 5; ++r) v[r] = __half22float2(hB2[r]);
      bf5s<1>(v);
      twchain<5>(v, tS1b);
#pragma unroll
      for (int r = 0; r < 5; ++r) a[j2 + 125 * r] = v[r];
    }
  }
  dif5_ip_stage_t<25>(a, ln, tS2a, tS2b);
  dif5_ip_stage_t<5>(a, ln, tS3a, tS3b);
  {
    float2 u[5], v[5];
#pragma unroll
    for (int r = 0; r < 5; ++r) u[r] = a[5 * j1 + r];
    if (g2) {
#pragma unroll
      for (int r = 0; r < 5; ++r) v[r] = a[5 * j2 + r];
    }
    bf5s<1>(u);
    if (g2) bf5s<1>(v);
    int rv1 = rev3_5(j1), rv2 = rev3_5(j2);
#pragma unroll
    for (int r = 0; r < 5; ++r) a[125 * r + rv1] = u[r];
    if (g2) {
#pragma unroll
      for (int r = 0; r < 5; ++r) a[125 * r + rv2] = v[r];
    }
  }
  for (int h = ln; h < NHOPS; h += 64) {
    float ex = 0.0f, ey = 0.0f;
#pragma unroll
    for (int d = 0; d < 4; ++d) {
      float2 z = a[4 * h + d];
      ex += z.x * z.x;
      ey += z.y * z.y;
    }
    Pw[h] += ex;
    Pw[NHOPS + h] += ey;
  }
  __syncthreads();   // the only block-wide barrier
  int eb = (sig * NB + band) * NHOPS;
  for (int idx = tid; idx < 2 * NHOPS; idx += 256) {
    float v = P[idx] + P[2 * NHOPS + idx] + P[4 * NHOPS + idx] + P[6 * NHOPS + idx];
    int comp = idx / NHOPS, h = idx - comp * NHOPS;
    atomicAdd(&E[comp * (BATCH * NB * NHOPS) + eb + h], v);
  }
}

// ---------- finalize: loudness, diff, softmax (H pre-scaled by 1/L -> SC = 1/2048) ----------
__global__ __launch_bounds__(1024) void finalize_kernel(const float* __restrict__ E,
                                                        float* __restrict__ out) {
  constexpr int ND = BATCH * NB * NCHUNK;  // 9920
  constexpr float SC = 1.0f / 2048.0f;
  __shared__ float diffs[ND];
  __shared__ float sred[1024];
  int tid = threadIdx.x;
  for (int idx = tid; idx < ND; idx += 1024) {
    int sb = idx / NCHUNK;
    int k = idx - sb * NCHUNK;
    float msw = (E[sb * NHOPS + k] + E[sb * NHOPS + k + 1]) * SC;
    float mso = (E[64 * NHOPS + sb * NHOPS + k] + E[64 * NHOPS + sb * NHOPS + k + 1]) * SC;
    float lw = -0.691f + 10.0f * log10f(msw + 1e-12f);
    float lo = -0.691f + 10.0f * log10f(mso + 1e-12f);
    diffs[idx] = lw - lo;
  }
  __syncthreads();
  float mx = -3.4e38f;
  for (int idx = tid; idx < ND; idx += 1024) mx = fmaxf(mx, diffs[idx]);
  sred[tid] = mx;
  __syncthreads();
  for (int s = 512; s > 0; s >>= 1) {
    if (tid < s) sred[tid] = fmaxf(sred[tid], sred[tid + s]);
    __syncthreads();
  }
  float gmax = sred[0];
  __syncthreads();
  float se = 0.0f, swd = 0.0f;
  for (int idx = tid; idx < ND; idx += 1024) {
    float d = diffs[idx];
    float e = expf(d - gmax);
    se += e;
    swd += d * e;
  }
  sred[tid] = se; __syncthreads();
  for (int s = 512; s > 0; s >>= 1) { if (tid < s) sred[tid] += sred[tid + s]; __syncthreads(); }
  float tot = sred[0];
  __syncthreads();
  sred[tid] = swd; __syncthreads();
  for (int s = 512; s > 0; s >>= 1) { if (tid < s) sred[tid] += sred[tid + s]; __syncthreads(); }
  if (tid == 0) out[0] = sred[0] / tot;
}

extern "C" void kernel_launch(void* const* d_in, const int* in_sizes, int n_in,
                              void* d_out, int out_size, void* d_ws, size_t ws_size,
                              hipStream_t stream) {
  (void)in_sizes; (void)n_in; (void)out_size; (void)ws_size;
  char* ws = (char*)d_ws;
  float2*  G = (float2*)ws;                        // 10,240,000 B
  __half2* H = (__half2*)(ws + 10240000);          // 40,960,000 B (fp16)
  float*   E = (float*)(ws + 51200000);            // 79,872 B [2][64][156]
  const float* w = (const float*)d_in[0];
  const float* o = (const float*)d_in[1];

  f1_kernel<<<dim3(BATCH * 64), dim3(256), 0, stream>>>(w, o, G, E);
  fi_kernel<<<dim3(4 * BATCH * 40), dim3(1024), 0, stream>>>(G, H);
  i2_kernel<<<dim3(BATCH * NB * 32), dim3(256), 0, stream>>>(H, E);
  finalize_kernel<<<dim3(1), dim3(1024), 0, stream>>>(E, (float*)d_out);
}